// Round 1
// baseline (885.540 us; speedup 1.0000x reference)
//
#include <hip/hip_runtime.h>
#include <math.h>

#define D_DIM   256
#define N_ROWS  16384
#define K_CODES 8192
#define BM      128
#define BN      128
#define DKC     32
#define KCHUNK  1024
#define PAD     4

// out layout: [0, 4194304) z_q_st | [4194304, 4210688) indices (as float) | [4210688] vq_loss
#define IDX_OFF  ((size_t)N_ROWS * D_DIM)
#define LOSS_OFF (IDX_OFF + N_ROWS)

// ws layout:
//   [0, 131072)        : unsigned long long keys[16384]
//   [131072, 163840)   : float enorm[8192]
//   [163840, 180224)   : float partials[4096]

__global__ __launch_bounds__(256) void init_keys_kernel(unsigned long long* __restrict__ keys) {
    int i = blockIdx.x * 256 + threadIdx.x;
    if (i < N_ROWS) keys[i] = ~0ULL;
}

__global__ __launch_bounds__(256) void enorm_kernel(const float* __restrict__ emb,
                                                    float* __restrict__ enorm) {
    int row  = blockIdx.x * 4 + (threadIdx.x >> 6);
    int lane = threadIdx.x & 63;
    float4 v = reinterpret_cast<const float4*>(emb + (size_t)row * D_DIM)[lane];
    float s = v.x * v.x + v.y * v.y + v.z * v.z + v.w * v.w;
    #pragma unroll
    for (int off = 32; off >= 1; off >>= 1) s += __shfl_down(s, off);
    if (lane == 0) enorm[row] = s;
}

__device__ __forceinline__ unsigned int f2ord(float f) {
    unsigned int u = __float_as_uint(f);
    return (u & 0x80000000u) ? ~u : (u | 0x80000000u);
}

__global__ __launch_bounds__(256, 2) void argmin_kernel(const float* __restrict__ z,
                                                        const float* __restrict__ emb,
                                                        const float* __restrict__ enorm,
                                                        unsigned long long* __restrict__ keys) {
    __shared__ float zs[DKC][BM + PAD];
    __shared__ float es[DKC][BN + PAD];

    const int tid   = threadIdx.x;
    const int tc    = tid & 15;   // code dim (16 threads)
    const int tr    = tid >> 4;   // row dim (16 threads)
    const int r0    = blockIdx.x * BM;
    const int cbase = blockIdx.y * KCHUNK;

    float best[8];
    int   bidx[8];
    #pragma unroll
    for (int i = 0; i < 8; ++i) { best[i] = INFINITY; bidx[i] = 0; }

    for (int ct = 0; ct < KCHUNK; ct += BN) {
        float acc[8][8];
        #pragma unroll
        for (int i = 0; i < 8; ++i)
            #pragma unroll
            for (int j = 0; j < 8; ++j) acc[i][j] = 0.0f;

        for (int d0 = 0; d0 < D_DIM; d0 += DKC) {
            __syncthreads();
            // stage z-tile (BM x DKC) and e-tile (BN x DKC), transposed to [d][row]
            #pragma unroll
            for (int it = 0; it < 4; ++it) {
                int q   = tid + it * 256;      // 0..1023
                int row = q >> 3;              // 0..127
                int f4  = q & 7;               // 0..7
                float4 vz = *reinterpret_cast<const float4*>(
                    &z[(size_t)(r0 + row) * D_DIM + d0 + f4 * 4]);
                zs[f4 * 4 + 0][row] = vz.x;
                zs[f4 * 4 + 1][row] = vz.y;
                zs[f4 * 4 + 2][row] = vz.z;
                zs[f4 * 4 + 3][row] = vz.w;
                float4 ve = *reinterpret_cast<const float4*>(
                    &emb[(size_t)(cbase + ct + row) * D_DIM + d0 + f4 * 4]);
                es[f4 * 4 + 0][row] = ve.x;
                es[f4 * 4 + 1][row] = ve.y;
                es[f4 * 4 + 2][row] = ve.z;
                es[f4 * 4 + 3][row] = ve.w;
            }
            __syncthreads();

            #pragma unroll 4
            for (int d = 0; d < DKC; ++d) {
                float a[8], b[8];
                #pragma unroll
                for (int i = 0; i < 8; ++i) a[i] = zs[d][tr * 8 + i];
                #pragma unroll
                for (int j = 0; j < 8; ++j) b[j] = es[d][tc * 8 + j];
                #pragma unroll
                for (int i = 0; i < 8; ++i)
                    #pragma unroll
                    for (int j = 0; j < 8; ++j)
                        acc[i][j] = fmaf(a[i], b[j], acc[i][j]);
            }
        }

        // epilogue: dist = enorm[c] - 2*dot  (|z|^2 dropped: row-constant)
        #pragma unroll
        for (int j = 0; j < 8; ++j) {
            int c = cbase + ct + tc * 8 + j;
            float en = enorm[c];
            #pragma unroll
            for (int i = 0; i < 8; ++i) {
                float dist = fmaf(-2.0f, acc[i][j], en);
                if (dist < best[i]) { best[i] = dist; bidx[i] = c; }
            }
        }
    }

    #pragma unroll
    for (int i = 0; i < 8; ++i) {
        unsigned long long key =
            ((unsigned long long)f2ord(best[i]) << 32) | (unsigned int)bidx[i];
        atomicMin(&keys[r0 + tr * 8 + i], key);
    }
}

__global__ __launch_bounds__(256) void gather_kernel(const float* __restrict__ z,
                                                     const float* __restrict__ emb,
                                                     const unsigned long long* __restrict__ keys,
                                                     float* __restrict__ out,
                                                     float* __restrict__ partials) {
    int row  = blockIdx.x * 4 + (threadIdx.x >> 6);
    int lane = threadIdx.x & 63;
    unsigned long long key = keys[row];
    unsigned int idx = (unsigned int)(key & 0xffffffffULL);
    if (lane == 0) out[IDX_OFF + row] = (float)idx;

    float4 e4 = reinterpret_cast<const float4*>(emb)[(size_t)idx * 64 + lane];
    float4 z4 = reinterpret_cast<const float4*>(z)[(size_t)row * 64 + lane];
    float tx = e4.x - z4.x, ty = e4.y - z4.y, tz = e4.z - z4.z, tw = e4.w - z4.w;
    float4 o;
    o.x = z4.x + tx; o.y = z4.y + ty; o.z = z4.z + tz; o.w = z4.w + tw;  // straight-through
    reinterpret_cast<float4*>(out)[(size_t)row * 64 + lane] = o;

    float s = tx * tx + ty * ty + tz * tz + tw * tw;
    #pragma unroll
    for (int off = 32; off >= 1; off >>= 1) s += __shfl_down(s, off);

    __shared__ float wsum[4];
    if (lane == 0) wsum[threadIdx.x >> 6] = s;
    __syncthreads();
    if (threadIdx.x == 0)
        partials[blockIdx.x] = (wsum[0] + wsum[1]) + (wsum[2] + wsum[3]);
}

__global__ __launch_bounds__(256) void loss_kernel(const float* __restrict__ partials,
                                                   float* __restrict__ out) {
    __shared__ float sm[256];
    float s = 0.0f;
    for (int i = threadIdx.x; i < 4096; i += 256) s += partials[i];
    sm[threadIdx.x] = s;
    __syncthreads();
    #pragma unroll
    for (int st = 128; st >= 1; st >>= 1) {
        if (threadIdx.x < st) sm[threadIdx.x] += sm[threadIdx.x + st];
        __syncthreads();
    }
    if (threadIdx.x == 0)
        out[LOSS_OFF] = sm[0] * (0.25f / (float)(N_ROWS * D_DIM));
}

extern "C" void kernel_launch(void* const* d_in, const int* in_sizes, int n_in,
                              void* d_out, int out_size, void* d_ws, size_t ws_size,
                              hipStream_t stream) {
    const float* z   = (const float*)d_in[0];
    const float* emb = (const float*)d_in[1];
    float* out = (float*)d_out;

    unsigned long long* keys = (unsigned long long*)d_ws;
    float* enorm    = (float*)((char*)d_ws + 131072);
    float* partials = (float*)((char*)d_ws + 163840);

    init_keys_kernel<<<N_ROWS / 256, 256, 0, stream>>>(keys);
    enorm_kernel<<<K_CODES / 4, 256, 0, stream>>>(emb, enorm);
    argmin_kernel<<<dim3(N_ROWS / BM, K_CODES / KCHUNK), 256, 0, stream>>>(z, emb, enorm, keys);
    gather_kernel<<<N_ROWS / 4, 256, 0, stream>>>(z, emb, keys, out, partials);
    loss_kernel<<<1, 256, 0, stream>>>(partials, out);
}

// Round 5
// 428.545 us; speedup vs baseline: 2.0664x; 2.0664x over previous
//
#include <hip/hip_runtime.h>
#include <math.h>

#define D_DIM   256
#define N_ROWS  16384
#define K_CODES 8192
#define BM      128
#define BN      128
#define DKC     64
#define KCHUNK  1024
#define NCHUNK  (K_CODES / KCHUNK)   // 8

typedef __attribute__((ext_vector_type(8))) short s8v;           // 8 bf16 (A/B frag)
typedef __attribute__((ext_vector_type(4))) float f4v;           // 4 f32  (C/D frag)
typedef __attribute__((ext_vector_type(4))) unsigned short us4;  // 4 bf16 (8B LDS write)
typedef unsigned long long u64;
typedef unsigned int u32;

// out layout: [0, 4194304) z_q_st | [4194304, 4210688) indices (as float) | [4210688] vq_loss
#define IDX_OFF  ((size_t)N_ROWS * D_DIM)
#define LOSS_OFF (IDX_OFF + N_ROWS)

// ws layout:
//   [0, 2 MB)            : u64 cand[N_ROWS][NCHUNK][2]   (top-2 keys per row per chunk)
//   [2 MB, 2 MB+32KB)    : float enorm[K_CODES]
//   [2 MB+32KB, +16KB)   : float partials[4096]
#define WS_ENORM_OFF    (2u * 1024u * 1024u)
#define WS_PARTIAL_OFF  (WS_ENORM_OFF + 32768u)

__device__ __forceinline__ unsigned short f2bf(float f) {   // fp32 -> bf16 RNE
    u32 u = __float_as_uint(f);
    return (unsigned short)((u + 0x7fffu + ((u >> 16) & 1u)) >> 16);
}
__device__ __forceinline__ float bf2f(unsigned short b) {
    return __uint_as_float(((u32)b) << 16);
}
__device__ __forceinline__ u32 f2ord(float f) {             // monotonic fp32 -> u32
    u32 u = __float_as_uint(f);
    return (u & 0x80000000u) ? ~u : (u | 0x80000000u);
}

__global__ __launch_bounds__(256) void enorm_kernel(const float* __restrict__ emb,
                                                    float* __restrict__ enorm) {
    int row  = blockIdx.x * 4 + (threadIdx.x >> 6);
    int lane = threadIdx.x & 63;
    float4 v = reinterpret_cast<const float4*>(emb + (size_t)row * D_DIM)[lane];
    float s = v.x * v.x + v.y * v.y + v.z * v.z + v.w * v.w;
    #pragma unroll
    for (int off = 32; off >= 1; off >>= 1) s += __shfl_down(s, off);
    if (lane == 0) enorm[row] = s;
}

// ---------------- MFMA argmin: top-2 per (row, chunk) ----------------
__global__ __launch_bounds__(256, 2) void argmin_kernel(const float* __restrict__ z,
                                                        const float* __restrict__ emb,
                                                        const float* __restrict__ enorm,
                                                        u64* __restrict__ cand) {
    // XOR-swizzled bf16 tiles: [128 rows][64 k], row stride 128 B, byte ^= (row&7)<<4
    __shared__ __align__(16) unsigned short zsh[BM * DKC];
    __shared__ __align__(16) unsigned short zsl[BM * DKC];
    __shared__ __align__(16) unsigned short esh[BN * DKC];
    __shared__ __align__(16) unsigned short esl[BN * DKC];

    const int tid = threadIdx.x;
    const int wv  = tid >> 6;          // wave 0..3 -> rows wv*32..+31
    const int l   = tid & 63;
    const int lr  = l & 15;            // A: row-in-frag / B: col-in-frag / D: col
    const int lg  = l >> 4;            // k-group; D: row-quad
    const int r0    = blockIdx.x * BM;
    const int cbase = blockIdx.y * KCHUNK;

    u64 t1[8], t2[8];                  // running top-2 key per owned row (i*4+r)
    #pragma unroll
    for (int q = 0; q < 8; ++q) { t1[q] = ~0ULL; t2[q] = ~0ULL; }

    // precompute frag row bases + swizzle masks
    int arb[2], asw[2], brb[8], bsw[8];
    #pragma unroll
    for (int i = 0; i < 2; ++i) {
        int row = wv * 32 + i * 16 + lr;
        arb[i] = row * 128; asw[i] = (row & 7) << 4;
    }
    #pragma unroll
    for (int j = 0; j < 8; ++j) {
        int row = j * 16 + lr;
        brb[j] = row * 128; bsw[j] = (row & 7) << 4;
    }

    for (int ct = 0; ct < KCHUNK; ct += BN) {
        f4v acc[2][8];
        #pragma unroll
        for (int i = 0; i < 2; ++i)
            #pragma unroll
            for (int j = 0; j < 8; ++j)
                acc[i][j] = (f4v){0.f, 0.f, 0.f, 0.f};

        for (int d0 = 0; d0 < D_DIM; d0 += DKC) {
            __syncthreads();
            // stage: fp32 -> (hi,lo) bf16, swizzled LDS writes
            #pragma unroll
            for (int it = 0; it < 8; ++it) {
                int q   = tid + it * 256;          // 0..2047
                int row = q >> 4;                  // 0..127
                int f4  = q & 15;                  // float4 slot along d
                int wo  = row * 128 + ((f4 * 8) ^ ((row & 7) << 4));

                float4 vz = *reinterpret_cast<const float4*>(
                    &z[(size_t)(r0 + row) * D_DIM + d0 + f4 * 4]);
                us4 h, lo;
                h[0] = f2bf(vz.x); lo[0] = f2bf(vz.x - bf2f(h[0]));
                h[1] = f2bf(vz.y); lo[1] = f2bf(vz.y - bf2f(h[1]));
                h[2] = f2bf(vz.z); lo[2] = f2bf(vz.z - bf2f(h[2]));
                h[3] = f2bf(vz.w); lo[3] = f2bf(vz.w - bf2f(h[3]));
                *reinterpret_cast<us4*>(reinterpret_cast<char*>(zsh) + wo) = h;
                *reinterpret_cast<us4*>(reinterpret_cast<char*>(zsl) + wo) = lo;

                float4 ve = *reinterpret_cast<const float4*>(
                    &emb[(size_t)(cbase + ct + row) * D_DIM + d0 + f4 * 4]);
                h[0] = f2bf(ve.x); lo[0] = f2bf(ve.x - bf2f(h[0]));
                h[1] = f2bf(ve.y); lo[1] = f2bf(ve.y - bf2f(h[1]));
                h[2] = f2bf(ve.z); lo[2] = f2bf(ve.z - bf2f(h[2]));
                h[3] = f2bf(ve.w); lo[3] = f2bf(ve.w - bf2f(h[3]));
                *reinterpret_cast<us4*>(reinterpret_cast<char*>(esh) + wo) = h;
                *reinterpret_cast<us4*>(reinterpret_cast<char*>(esl) + wo) = lo;
            }
            __syncthreads();

            #pragma unroll
            for (int kf = 0; kf < 2; ++kf) {
                const int kb = kf * 64 + lg * 16;   // byte offset of lane's 8 bf16
                s8v ah[2], al[2];
                #pragma unroll
                for (int i = 0; i < 2; ++i) {
                    int o = arb[i] + (kb ^ asw[i]);
                    ah[i] = *reinterpret_cast<const s8v*>(reinterpret_cast<const char*>(zsh) + o);
                    al[i] = *reinterpret_cast<const s8v*>(reinterpret_cast<const char*>(zsl) + o);
                }
                #pragma unroll
                for (int jh = 0; jh < 2; ++jh) {
                    s8v bh[4], bl[4];
                    #pragma unroll
                    for (int jj = 0; jj < 4; ++jj) {
                        int j = jh * 4 + jj;
                        int o = brb[j] + (kb ^ bsw[j]);
                        bh[jj] = *reinterpret_cast<const s8v*>(reinterpret_cast<const char*>(esh) + o);
                        bl[jj] = *reinterpret_cast<const s8v*>(reinterpret_cast<const char*>(esl) + o);
                    }
                    #pragma unroll
                    for (int i = 0; i < 2; ++i)
                        #pragma unroll
                        for (int jj = 0; jj < 4; ++jj) {
                            int j = jh * 4 + jj;
                            acc[i][j] = __builtin_amdgcn_mfma_f32_16x16x32_bf16(ah[i], bh[jj], acc[i][j], 0, 0, 0);
                            acc[i][j] = __builtin_amdgcn_mfma_f32_16x16x32_bf16(ah[i], bl[jj], acc[i][j], 0, 0, 0);
                            acc[i][j] = __builtin_amdgcn_mfma_f32_16x16x32_bf16(al[i], bh[jj], acc[i][j], 0, 0, 0);
                        }
                }
            }
        }

        // epilogue: dist = enorm[c] - 2*dot ; reduce over j, update per-row top-2
        float en[8];
        #pragma unroll
        for (int j = 0; j < 8; ++j) en[j] = enorm[cbase + ct + j * 16 + lr];

        #pragma unroll
        for (int i = 0; i < 2; ++i)
            #pragma unroll
            for (int r = 0; r < 4; ++r) {
                float m = fmaf(-2.f, acc[i][0][r], en[0]);
                int  mj = 0;
                #pragma unroll
                for (int j = 1; j < 8; ++j) {
                    float dj = fmaf(-2.f, acc[i][j][r], en[j]);
                    if (dj < m) { m = dj; mj = j; }
                }
                u32 c = (u32)(cbase + ct + mj * 16 + lr);
                u64 key = ((u64)f2ord(m) << 32) | c;
                int q = i * 4 + r;
                if (key < t1[q])      { t2[q] = t1[q]; t1[q] = key; }
                else if (key < t2[q]) { t2[q] = key; }
            }
    }

    // cross-lane top-2 merge within each 16-lane group, then write cand
    #pragma unroll
    for (int i = 0; i < 2; ++i)
        #pragma unroll
        for (int r = 0; r < 4; ++r) {
            int q = i * 4 + r;
            u64 a1 = t1[q], a2 = t2[q];
            #pragma unroll
            for (int mk = 1; mk <= 8; mk <<= 1) {
                u64 o1 = __shfl_xor(a1, mk);
                u64 o2 = __shfl_xor(a2, mk);
                u64 n1 = a1 < o1 ? a1 : o1;
                u64 hi = a1 < o1 ? o1 : a1;
                u64 m2 = a2 < o2 ? a2 : o2;
                a1 = n1;
                a2 = hi < m2 ? hi : m2;
            }
            if (lr == 0) {
                int row_g = r0 + wv * 32 + i * 16 + lg * 4 + r;
                u64* dst = &cand[((size_t)row_g * NCHUNK + blockIdx.y) * 2];
                dst[0] = a1; dst[1] = a2;
            }
        }
}

// ---------------- exact fp32 rescore of 16 candidates + outputs ----------------
__global__ __launch_bounds__(256) void rescore_kernel(const float* __restrict__ z,
                                                      const float* __restrict__ emb,
                                                      const float* __restrict__ enorm,
                                                      const u64* __restrict__ cand,
                                                      float* __restrict__ out,
                                                      float* __restrict__ partials) {
    int row  = blockIdx.x * 4 + (threadIdx.x >> 6);
    int lane = threadIdx.x & 63;
    float4 zv = reinterpret_cast<const float4*>(z)[(size_t)row * 64 + lane];

    u64 best = ~0ULL;
    for (int s = 0; s < 2 * NCHUNK; ++s) {
        u32 c = ((u32)cand[(size_t)row * (2 * NCHUNK) + s]) & (K_CODES - 1);
        float4 ev = reinterpret_cast<const float4*>(emb)[(size_t)c * 64 + lane];
        float p = zv.x * ev.x + zv.y * ev.y + zv.z * ev.z + zv.w * ev.w;
        #pragma unroll
        for (int mk = 1; mk < 64; mk <<= 1) p += __shfl_xor(p, mk);
        float dist = fmaf(-2.f, p, enorm[c]);
        u64 key = ((u64)f2ord(dist) << 32) | c;
        best = key < best ? key : best;
    }
    u32 idx = ((u32)best) & (K_CODES - 1);
    if (lane == 0) out[IDX_OFF + row] = (float)idx;

    float4 ev = reinterpret_cast<const float4*>(emb)[(size_t)idx * 64 + lane];
    float tx = ev.x - zv.x, ty = ev.y - zv.y, tz = ev.z - zv.z, tw = ev.w - zv.w;
    float4 o;
    o.x = zv.x + tx; o.y = zv.y + ty; o.z = zv.z + tz; o.w = zv.w + tw;  // straight-through
    reinterpret_cast<float4*>(out)[(size_t)row * 64 + lane] = o;

    float s = tx * tx + ty * ty + tz * tz + tw * tw;
    #pragma unroll
    for (int off = 32; off >= 1; off >>= 1) s += __shfl_down(s, off);

    __shared__ float wsum[4];
    if (lane == 0) wsum[threadIdx.x >> 6] = s;
    __syncthreads();
    if (threadIdx.x == 0)
        partials[blockIdx.x] = (wsum[0] + wsum[1]) + (wsum[2] + wsum[3]);
}

__global__ __launch_bounds__(256) void loss_kernel(const float* __restrict__ partials,
                                                   float* __restrict__ out) {
    __shared__ float sm[256];
    float s = 0.0f;
    for (int i = threadIdx.x; i < 4096; i += 256) s += partials[i];
    sm[threadIdx.x] = s;
    __syncthreads();
    #pragma unroll
    for (int st = 128; st >= 1; st >>= 1) {
        if (threadIdx.x < st) sm[threadIdx.x] += sm[threadIdx.x + st];
        __syncthreads();
    }
    if (threadIdx.x == 0)
        out[LOSS_OFF] = sm[0] * (0.25f / (float)(N_ROWS * D_DIM));
}

extern "C" void kernel_launch(void* const* d_in, const int* in_sizes, int n_in,
                              void* d_out, int out_size, void* d_ws, size_t ws_size,
                              hipStream_t stream) {
    const float* z   = (const float*)d_in[0];
    const float* emb = (const float*)d_in[1];
    float* out = (float*)d_out;

    u64*   cand     = (u64*)d_ws;
    float* enorm    = (float*)((char*)d_ws + WS_ENORM_OFF);
    float* partials = (float*)((char*)d_ws + WS_PARTIAL_OFF);

    enorm_kernel<<<K_CODES / 4, 256, 0, stream>>>(emb, enorm);
    argmin_kernel<<<dim3(N_ROWS / BM, NCHUNK), 256, 0, stream>>>(z, emb, enorm, cand);
    rescore_kernel<<<N_ROWS / 4, 256, 0, stream>>>(z, emb, enorm, cand, out, partials);
    loss_kernel<<<1, 256, 0, stream>>>(partials, out);
}